// Round 2
// 107.522 us; speedup vs baseline: 1.1495x; 1.1495x over previous
//
#include <hip/hip_runtime.h>

#define B_    16384
#define I_    35
#define E_    256
#define KP    224          // packed K: 6 bf16 per i (210) padded to 224 = 7 k-steps of 32
#define F_    140          // 4*I_ (metadata row stride in floats)
#define MROWS 32
#define NBLK  (B_ / MROWS) // 512
#define LROW  232          // feat LDS row stride in ushorts (464 B, 16B-aligned, 2-way-bank-free)

typedef short bf16x8 __attribute__((ext_vector_type(8)));  // 8 bf16 = 4 VGPRs
typedef float f32x4  __attribute__((ext_vector_type(4)));  // MFMA C/D

__device__ __forceinline__ unsigned short f2bf(float f) {
    unsigned int u = __float_as_uint(f);
    u += 0x7FFFu + ((u >> 16) & 1u);               // RNE
    return (unsigned short)(u >> 16);
}

// One block per output channel e, 512 threads = 32 sixteen-lane groups.
// Each group owns one (i,part) unit: part 0/1/2 = d/c/r (dot + bias-dot),
// part 3 = the 4 embedding dots sharing one Wf slice (register reuse).
// All global loads are 16-lane coalesced; Wf is consumed straight from
// global exactly once (no LDS staging phase). Output row is written at the
// PERMUTED position v so the main kernel can do float4 epilogue IO.
__global__ __launch_bounds__(512) void precompute_kernel(
    const float* __restrict__ Wd, const float* __restrict__ bd,
    const float* __restrict__ Wc, const float* __restrict__ bc,
    const float* __restrict__ Wr, const float* __restrict__ br,
    const float* __restrict__ emb, const float* __restrict__ Wf,
    const float* __restrict__ bf,
    unsigned short* __restrict__ At, float* __restrict__ base)
{
    __shared__ float dots[7][40];
    __shared__ float bds[3][40];
    const int e = blockIdx.x, t = threadIdx.x;
    const int grp = t >> 4, gl = t & 15;           // 32 groups x 16 lanes

    const float* wfrow = Wf + (size_t)e * 8960;

    for (int u = grp; u < 140; u += 32) {
        const int i = u >> 2, part = u & 3;        // part fixed per group (grp&3)
        const float* wf = wfrow + i * 256 + part * 64;
        float wv[4];
        #pragma unroll
        for (int j = 0; j < 4; ++j) wv[j] = wf[gl + 16 * j];   // coalesced, read once
        if (part < 3) {
            const float* tab  = ((part == 0) ? Wd : (part == 1) ? Wc : Wr) + i * 64;
            const float* btab = ((part == 0) ? bd : (part == 1) ? bc : br) + i * 64;
            float dot = 0.f, bdot = 0.f;
            #pragma unroll
            for (int j = 0; j < 4; ++j) {
                const int c = gl + 16 * j;
                dot  = fmaf(tab[c],  wv[j], dot);
                bdot = fmaf(btab[c], wv[j], bdot);
            }
            #pragma unroll
            for (int mm = 1; mm < 16; mm <<= 1) {
                dot  += __shfl_xor(dot,  mm, 64);
                bdot += __shfl_xor(bdot, mm, 64);
            }
            if (gl == 0) { dots[part][i] = dot; bds[part][i] = bdot; }
        } else {
            const float* et = emb + (size_t)i * 256;
            float d0 = 0.f, d1 = 0.f, d2 = 0.f, d3 = 0.f;
            #pragma unroll
            for (int j = 0; j < 4; ++j) {
                const int c = gl + 16 * j;
                d0 = fmaf(et[c],       wv[j], d0);
                d1 = fmaf(et[64 + c],  wv[j], d1);
                d2 = fmaf(et[128 + c], wv[j], d2);
                d3 = fmaf(et[192 + c], wv[j], d3);
            }
            #pragma unroll
            for (int mm = 1; mm < 16; mm <<= 1) {
                d0 += __shfl_xor(d0, mm, 64);
                d1 += __shfl_xor(d1, mm, 64);
                d2 += __shfl_xor(d2, mm, 64);
                d3 += __shfl_xor(d3, mm, 64);
            }
            if (gl == 0) { dots[3][i] = d0; dots[4][i] = d1; dots[5][i] = d2; dots[6][i] = d3; }
        }
    }
    __syncthreads();

    // virtual row v: main's wave w / lane nlo reads acc column nn from At row
    // w*64 + nn*16 + nlo; we want its ACTUAL channel to be w*64 + nlo*4 + nn.
    const int v = (e & ~63) | ((e & 3) << 4) | ((e & 63) >> 2);

    if (t < I_) {
        const float v0 = dots[3][t], v1 = dots[4][t], v2 = dots[5][t], v3 = dots[6][t];
        const float a = v1 - v0, b = v2 - v0, c = v3 - v0;
        const float k2 = 0.5f * (a + b);
        const float s  = 0.5f * (a - b);           // k1 + k3
        const float uu = 0.5f * (4.f * k2 - c);    // k1 + 4*k3
        const float k3 = (uu - s) * (1.f / 3.f);
        const float k1 = s - k3;
        unsigned int* dst = (unsigned int*)(At + (size_t)v * KP + t * 6);
        dst[0] = (unsigned int)f2bf(dots[0][t]) | ((unsigned int)f2bf(dots[1][t]) << 16);
        dst[1] = (unsigned int)f2bf(dots[2][t]) | ((unsigned int)f2bf(k1) << 16);
        dst[2] = (unsigned int)f2bf(k2)         | ((unsigned int)f2bf(k3) << 16);
    } else if (t < I_ + 7) {                       // zero K-pad 210..223 (7 dwords)
        ((unsigned int*)(At + (size_t)v * KP))[105 + t - I_] = 0;
    }
    if (t < 64) {                                  // base[e] = bf + bias dots + sum k0
        float part = (t < I_) ? (bds[0][t] + bds[1][t] + bds[2][t] + dots[3][t]) : 0.f;
        #pragma unroll
        for (int mm = 1; mm < 64; mm <<= 1) part += __shfl_xor(part, mm, 64);
        if (t == 0) base[e] = bf[e] + part;
    }
}

// out(16384 x 256) = feat(16384 x 224) @ AcombT^T via 16x16x32 bf16 MFMA,
// fused bias + LayerNorm + ReLU. Block = 32 rows x all 256 channels, 4 waves.
// Channel-permuted At makes each lane own 4 consecutive actual channels ->
// float4 stores (256 B contiguous per 16-lane quarter) and float4 param loads.
__global__ __launch_bounds__(256) void main_kernel(
    const float* __restrict__ metadata,
    const unsigned short* __restrict__ At,
    const float* __restrict__ base,
    const float* __restrict__ gamma, const float* __restrict__ beta,
    float* __restrict__ out)
{
    __shared__ unsigned short feat[MROWS * LROW];
    __shared__ float redS[4][MROWS];
    __shared__ float redQ[4][MROWS];

    const int t  = threadIdx.x;
    const int b0 = blockIdx.x * MROWS;

    const int lane = t & 63, w = t >> 6;
    const int nlo = lane & 15, q = lane >> 4;

    // Epilogue params for this lane's 4 ACTUAL channels e = w*64 + nlo*4 + nn.
    const float4 bs4 = *(const float4*)(base  + w * 64 + nlo * 4);
    const float4 gm4 = *(const float4*)(gamma + w * 64 + nlo * 4);
    const float4 bt4 = *(const float4*)(beta  + w * 64 + nlo * 4);
    const float bsv[4] = {bs4.x, bs4.y, bs4.z, bs4.w};
    const float gmv[4] = {gm4.x, gm4.y, gm4.z, gm4.w};
    const float btv[4] = {bt4.x, bt4.y, bt4.z, bt4.w};

    // Build packed bf16 feature rows [d,c,rl,x,x^2,x^3] per i (6 shorts = 3 dwords).
    for (int cell = t; cell < MROWS * I_; cell += 256) {
        const int r = cell / I_, i = cell - r * I_;
        const float* mp = metadata + (size_t)(b0 + r) * F_ + i;
        const float d = mp[0], c = mp[I_], rl = mp[2 * I_], x = mp[3 * I_];
        const float x2 = x * x, x3 = x2 * x;
        unsigned int* dw = (unsigned int*)(feat + r * LROW + i * 6);
        dw[0] = (unsigned int)f2bf(d)  | ((unsigned int)f2bf(c)  << 16);
        dw[1] = (unsigned int)f2bf(rl) | ((unsigned int)f2bf(x)  << 16);
        dw[2] = (unsigned int)f2bf(x2) | ((unsigned int)f2bf(x3) << 16);
    }
    for (int z = t; z < MROWS * 7; z += 256) {      // zero K-pad 210..223 per row
        const int r = z / 7, j = z - r * 7;
        ((unsigned int*)(feat + r * LROW + 210))[j] = 0;
    }
    __syncthreads();

    f32x4 acc[2][4];
    #pragma unroll
    for (int mt = 0; mt < 2; ++mt)
        #pragma unroll
        for (int nn = 0; nn < 4; ++nn) acc[mt][nn] = (f32x4){0.f, 0.f, 0.f, 0.f};

    // A-frag: lane holds feat[m = nlo][k = q*8 + j]; B-frag: At[v = w*64+nn*16+nlo][k]
    const unsigned short* ga = feat + nlo * LROW + q * 8;
    const unsigned short* gb = At + ((size_t)(w * 64 + nlo)) * KP + q * 8;

    #pragma unroll
    for (int ks = 0; ks < KP / 32; ++ks) {
        const bf16x8 a0 = *(const bf16x8*)(ga + ks * 32);
        const bf16x8 a1 = *(const bf16x8*)(ga + 16 * LROW + ks * 32);
        #pragma unroll
        for (int nn = 0; nn < 4; ++nn) {
            const bf16x8 b = *(const bf16x8*)(gb + (size_t)nn * 16 * KP + ks * 32);
            acc[0][nn] = __builtin_amdgcn_mfma_f32_16x16x32_bf16(a0, b, acc[0][nn], 0, 0, 0);
            acc[1][nn] = __builtin_amdgcn_mfma_f32_16x16x32_bf16(a1, b, acc[1][nn], 0, 0, 0);
        }
    }

    // Per-row moments: C/D layout row = q*4+reg (+16*mt), col = nlo (+16*nn).
    #pragma unroll
    for (int mt = 0; mt < 2; ++mt) {
        #pragma unroll
        for (int reg = 0; reg < 4; ++reg) {
            float s = 0.f, qq = 0.f;
            #pragma unroll
            for (int nn = 0; nn < 4; ++nn) {
                const float vv = acc[mt][nn][reg] + bsv[nn];
                acc[mt][nn][reg] = vv;
                s += vv; qq += vv * vv;
            }
            #pragma unroll
            for (int mm = 1; mm < 16; mm <<= 1) {   // reduce over the 16 e-lanes
                s  += __shfl_xor(s, mm, 64);
                qq += __shfl_xor(qq, mm, 64);
            }
            if (nlo == 0) {
                const int row = mt * 16 + q * 4 + reg;
                redS[w][row] = s; redQ[w][row] = qq;
            }
        }
    }
    __syncthreads();

    #pragma unroll
    for (int mt = 0; mt < 2; ++mt) {
        #pragma unroll
        for (int reg = 0; reg < 4; ++reg) {
            const int row = mt * 16 + q * 4 + reg;
            const float S = redS[0][row] + redS[1][row] + redS[2][row] + redS[3][row];
            const float Q = redQ[0][row] + redQ[1][row] + redQ[2][row] + redQ[3][row];
            const float mu   = S * (1.f / E_);
            const float var  = Q * (1.f / E_) - mu * mu;
            const float rstd = rsqrtf(var + 1e-5f);
            float4 o;
            o.x = fmaxf((acc[mt][0][reg] - mu) * rstd * gmv[0] + btv[0], 0.f);
            o.y = fmaxf((acc[mt][1][reg] - mu) * rstd * gmv[1] + btv[1], 0.f);
            o.z = fmaxf((acc[mt][2][reg] - mu) * rstd * gmv[2] + btv[2], 0.f);
            o.w = fmaxf((acc[mt][3][reg] - mu) * rstd * gmv[3] + btv[3], 0.f);
            *(float4*)(out + (size_t)(b0 + row) * E_ + w * 64 + nlo * 4) = o;
        }
    }
}

extern "C" void kernel_launch(void* const* d_in, const int* in_sizes, int n_in,
                              void* d_out, int out_size, void* d_ws, size_t ws_size,
                              hipStream_t stream) {
    const float* metadata = (const float*)d_in[0];
    const float* Wd  = (const float*)d_in[1];
    const float* bd  = (const float*)d_in[2];
    const float* Wc  = (const float*)d_in[3];
    const float* bc  = (const float*)d_in[4];
    const float* Wr  = (const float*)d_in[5];
    const float* br  = (const float*)d_in[6];
    const float* emb = (const float*)d_in[7];
    const float* Wf  = (const float*)d_in[8];
    const float* bf  = (const float*)d_in[9];
    const float* gamma = (const float*)d_in[10];
    const float* beta  = (const float*)d_in[11];

    unsigned short* At = (unsigned short*)d_ws;                    // 256*224*2 = 114688 B
    float* basep = (float*)((char*)d_ws + (size_t)E_ * KP * 2);    // 1 KB

    precompute_kernel<<<E_, 512, 0, stream>>>(Wd, bd, Wc, bc, Wr, br, emb, Wf, bf,
                                              At, basep);
    main_kernel<<<NBLK, 256, 0, stream>>>(metadata, At, basep, gamma, beta,
                                          (float*)d_out);
}

// Round 4
// 106.187 us; speedup vs baseline: 1.1640x; 1.0126x over previous
//
#include <hip/hip_runtime.h>

#define B_    16384
#define I_    35
#define E_    256
#define KP    224          // packed K: 6 bf16 per i (210) padded to 224 = 7 k-steps of 32
#define F_    140          // 4*I_ (metadata row stride in floats)
#define MROWS 32
#define NBLK  (B_ / MROWS) // 512
#define LROW  232          // feat LDS row stride in ushorts (464 B, 16B-aligned, 2-way-bank-free)

typedef short bf16x8 __attribute__((ext_vector_type(8)));  // 8 bf16 = 4 VGPRs
typedef float f32x4  __attribute__((ext_vector_type(4)));  // MFMA C/D

__device__ __forceinline__ unsigned short f2bf(float f) {
    unsigned int u = __float_as_uint(f);
    u += 0x7FFFu + ((u >> 16) & 1u);               // RNE
    return (unsigned short)(u >> 16);
}

// One block per output channel e, 512 threads = 32 sixteen-lane groups.
// Each group owns one (i,part) unit: part 0/1/2 = d/c/r (dot + bias-dot),
// part 3 = the 4 embedding dots sharing one Wf slice (register reuse).
// All global loads are 16-lane coalesced; Wf is consumed straight from
// global exactly once (no LDS staging phase). Output row is written at the
// PERMUTED position v so the main kernel can do float4 epilogue IO.
__global__ __launch_bounds__(512) void precompute_kernel(
    const float* __restrict__ Wd, const float* __restrict__ bd,
    const float* __restrict__ Wc, const float* __restrict__ bc,
    const float* __restrict__ Wr, const float* __restrict__ br,
    const float* __restrict__ emb, const float* __restrict__ Wf,
    const float* __restrict__ bf,
    unsigned short* __restrict__ At, float* __restrict__ base)
{
    __shared__ float dots[7][40];
    __shared__ float bds[3][40];
    const int e = blockIdx.x, t = threadIdx.x;
    const int grp = t >> 4, gl = t & 15;           // 32 groups x 16 lanes

    const float* wfrow = Wf + (size_t)e * 8960;

    for (int u = grp; u < 140; u += 32) {
        const int i = u >> 2, part = u & 3;        // part fixed per group (grp&3)
        const float* wf = wfrow + i * 256 + part * 64;
        float wv[4];
        #pragma unroll
        for (int j = 0; j < 4; ++j) wv[j] = wf[gl + 16 * j];   // coalesced, read once
        if (part < 3) {
            const float* tab  = ((part == 0) ? Wd : (part == 1) ? Wc : Wr) + i * 64;
            const float* btab = ((part == 0) ? bd : (part == 1) ? bc : br) + i * 64;
            float dot = 0.f, bdot = 0.f;
            #pragma unroll
            for (int j = 0; j < 4; ++j) {
                const int c = gl + 16 * j;
                dot  = fmaf(tab[c],  wv[j], dot);
                bdot = fmaf(btab[c], wv[j], bdot);
            }
            #pragma unroll
            for (int mm = 1; mm < 16; mm <<= 1) {
                dot  += __shfl_xor(dot,  mm, 64);
                bdot += __shfl_xor(bdot, mm, 64);
            }
            if (gl == 0) { dots[part][i] = dot; bds[part][i] = bdot; }
        } else {
            const float* et = emb + (size_t)i * 256;
            float d0 = 0.f, d1 = 0.f, d2 = 0.f, d3 = 0.f;
            #pragma unroll
            for (int j = 0; j < 4; ++j) {
                const int c = gl + 16 * j;
                d0 = fmaf(et[c],       wv[j], d0);
                d1 = fmaf(et[64 + c],  wv[j], d1);
                d2 = fmaf(et[128 + c], wv[j], d2);
                d3 = fmaf(et[192 + c], wv[j], d3);
            }
            #pragma unroll
            for (int mm = 1; mm < 16; mm <<= 1) {
                d0 += __shfl_xor(d0, mm, 64);
                d1 += __shfl_xor(d1, mm, 64);
                d2 += __shfl_xor(d2, mm, 64);
                d3 += __shfl_xor(d3, mm, 64);
            }
            if (gl == 0) { dots[3][i] = d0; dots[4][i] = d1; dots[5][i] = d2; dots[6][i] = d3; }
        }
    }
    __syncthreads();

    // virtual row v: main's wave w / lane nlo reads acc column nn from At row
    // w*64 + nn*16 + nlo; we want its ACTUAL channel to be w*64 + nlo*4 + nn.
    const int v = (e & ~63) | ((e & 3) << 4) | ((e & 63) >> 2);

    if (t < I_) {
        const float v0 = dots[3][t], v1 = dots[4][t], v2 = dots[5][t], v3 = dots[6][t];
        const float a = v1 - v0, b = v2 - v0, c = v3 - v0;
        const float k2 = 0.5f * (a + b);
        const float s  = 0.5f * (a - b);           // k1 + k3
        const float uu = 0.5f * (4.f * k2 - c);    // k1 + 4*k3
        const float k3 = (uu - s) * (1.f / 3.f);
        const float k1 = s - k3;
        unsigned int* dst = (unsigned int*)(At + (size_t)v * KP + t * 6);
        dst[0] = (unsigned int)f2bf(dots[0][t]) | ((unsigned int)f2bf(dots[1][t]) << 16);
        dst[1] = (unsigned int)f2bf(dots[2][t]) | ((unsigned int)f2bf(k1) << 16);
        dst[2] = (unsigned int)f2bf(k2)         | ((unsigned int)f2bf(k3) << 16);
    } else if (t < I_ + 7) {                       // zero K-pad 210..223 (7 dwords)
        ((unsigned int*)(At + (size_t)v * KP))[105 + t - I_] = 0;
    }
    if (t < 64) {                                  // base[e] = bf + bias dots + sum k0
        float part = (t < I_) ? (bds[0][t] + bds[1][t] + bds[2][t] + dots[3][t]) : 0.f;
        #pragma unroll
        for (int mm = 1; mm < 64; mm <<= 1) part += __shfl_xor(part, mm, 64);
        if (t == 0) base[e] = bf[e] + part;
    }
}

// out(16384 x 256) = feat(16384 x 224) @ AcombT^T via 16x16x32 bf16 MFMA,
// fused bias + LayerNorm + ReLU. Block = 32 rows x all 256 channels, 4 waves.
// Channel-permuted At makes each lane own 4 consecutive actual channels ->
// float4 stores (256 B contiguous per 16-lane quarter) and float4 param loads.
__global__ __launch_bounds__(256) void main_kernel(
    const float* __restrict__ metadata,
    const unsigned short* __restrict__ At,
    const float* __restrict__ base,
    const float* __restrict__ gamma, const float* __restrict__ beta,
    float* __restrict__ out)
{
    __shared__ unsigned short feat[MROWS * LROW];
    __shared__ float redS[4][MROWS];
    __shared__ float redQ[4][MROWS];

    const int t  = threadIdx.x;
    const int b0 = blockIdx.x * MROWS;

    const int lane = t & 63, w = t >> 6;
    const int nlo = lane & 15, q = lane >> 4;

    // Epilogue params for this lane's 4 ACTUAL channels e = w*64 + nlo*4 + nn.
    const float4 bs4 = *(const float4*)(base  + w * 64 + nlo * 4);
    const float4 gm4 = *(const float4*)(gamma + w * 64 + nlo * 4);
    const float4 bt4 = *(const float4*)(beta  + w * 64 + nlo * 4);
    const float bsv[4] = {bs4.x, bs4.y, bs4.z, bs4.w};
    const float gmv[4] = {gm4.x, gm4.y, gm4.z, gm4.w};
    const float btv[4] = {bt4.x, bt4.y, bt4.z, bt4.w};

    // Build packed bf16 feature rows [d,c,rl,x,x^2,x^3] per i (6 shorts = 3 dwords).
    for (int cell = t; cell < MROWS * I_; cell += 256) {
        const int r = cell / I_, i = cell - r * I_;
        const float* mp = metadata + (size_t)(b0 + r) * F_ + i;
        const float d = mp[0], c = mp[I_], rl = mp[2 * I_], x = mp[3 * I_];
        const float x2 = x * x, x3 = x2 * x;
        unsigned int* dw = (unsigned int*)(feat + r * LROW + i * 6);
        dw[0] = (unsigned int)f2bf(d)  | ((unsigned int)f2bf(c)  << 16);
        dw[1] = (unsigned int)f2bf(rl) | ((unsigned int)f2bf(x)  << 16);
        dw[2] = (unsigned int)f2bf(x2) | ((unsigned int)f2bf(x3) << 16);
    }
    for (int z = t; z < MROWS * 7; z += 256) {      // zero K-pad 210..223 per row
        const int r = z / 7, j = z - r * 7;
        ((unsigned int*)(feat + r * LROW + 210))[j] = 0;
    }
    __syncthreads();

    f32x4 acc[2][4];
    #pragma unroll
    for (int mt = 0; mt < 2; ++mt)
        #pragma unroll
        for (int nn = 0; nn < 4; ++nn) acc[mt][nn] = (f32x4){0.f, 0.f, 0.f, 0.f};

    // A-frag: lane holds feat[m = nlo][k = q*8 + j]; B-frag: At[v = w*64+nn*16+nlo][k]
    const unsigned short* ga = feat + nlo * LROW + q * 8;
    const unsigned short* gb = At + ((size_t)(w * 64 + nlo)) * KP + q * 8;

    #pragma unroll
    for (int ks = 0; ks < KP / 32; ++ks) {
        const bf16x8 a0 = *(const bf16x8*)(ga + ks * 32);
        const bf16x8 a1 = *(const bf16x8*)(ga + 16 * LROW + ks * 32);
        #pragma unroll
        for (int nn = 0; nn < 4; ++nn) {
            const bf16x8 b = *(const bf16x8*)(gb + (size_t)nn * 16 * KP + ks * 32);
            acc[0][nn] = __builtin_amdgcn_mfma_f32_16x16x32_bf16(a0, b, acc[0][nn], 0, 0, 0);
            acc[1][nn] = __builtin_amdgcn_mfma_f32_16x16x32_bf16(a1, b, acc[1][nn], 0, 0, 0);
        }
    }

    // Per-row moments: C/D layout row = q*4+reg (+16*mt), col = nlo (+16*nn).
    #pragma unroll
    for (int mt = 0; mt < 2; ++mt) {
        #pragma unroll
        for (int reg = 0; reg < 4; ++reg) {
            float s = 0.f, qq = 0.f;
            #pragma unroll
            for (int nn = 0; nn < 4; ++nn) {
                const float vv = acc[mt][nn][reg] + bsv[nn];
                acc[mt][nn][reg] = vv;
                s += vv; qq += vv * vv;
            }
            #pragma unroll
            for (int mm = 1; mm < 16; mm <<= 1) {   // reduce over the 16 e-lanes
                s  += __shfl_xor(s, mm, 64);
                qq += __shfl_xor(qq, mm, 64);
            }
            if (nlo == 0) {
                const int row = mt * 16 + q * 4 + reg;
                redS[w][row] = s; redQ[w][row] = qq;
            }
        }
    }
    __syncthreads();

    #pragma unroll
    for (int mt = 0; mt < 2; ++mt) {
        #pragma unroll
        for (int reg = 0; reg < 4; ++reg) {
            const int row = mt * 16 + q * 4 + reg;
            const float S = redS[0][row] + redS[1][row] + redS[2][row] + redS[3][row];
            const float Q = redQ[0][row] + redQ[1][row] + redQ[2][row] + redQ[3][row];
            const float mu   = S * (1.f / E_);
            const float var  = Q * (1.f / E_) - mu * mu;
            const float rstd = rsqrtf(var + 1e-5f);
            float4 o;
            o.x = fmaxf((acc[mt][0][reg] - mu) * rstd * gmv[0] + btv[0], 0.f);
            o.y = fmaxf((acc[mt][1][reg] - mu) * rstd * gmv[1] + btv[1], 0.f);
            o.z = fmaxf((acc[mt][2][reg] - mu) * rstd * gmv[2] + btv[2], 0.f);
            o.w = fmaxf((acc[mt][3][reg] - mu) * rstd * gmv[3] + btv[3], 0.f);
            *(float4*)(out + (size_t)(b0 + row) * E_ + w * 64 + nlo * 4) = o;
        }
    }
}

extern "C" void kernel_launch(void* const* d_in, const int* in_sizes, int n_in,
                              void* d_out, int out_size, void* d_ws, size_t ws_size,
                              hipStream_t stream) {
    const float* metadata = (const float*)d_in[0];
    const float* Wd  = (const float*)d_in[1];
    const float* bd  = (const float*)d_in[2];
    const float* Wc  = (const float*)d_in[3];
    const float* bc  = (const float*)d_in[4];
    const float* Wr  = (const float*)d_in[5];
    const float* br  = (const float*)d_in[6];
    const float* emb = (const float*)d_in[7];
    const float* Wf  = (const float*)d_in[8];
    const float* bf  = (const float*)d_in[9];
    const float* gamma = (const float*)d_in[10];
    const float* beta  = (const float*)d_in[11];

    unsigned short* At = (unsigned short*)d_ws;                    // 256*224*2 = 114688 B
    float* basep = (float*)((char*)d_ws + (size_t)E_ * KP * 2);    // 1 KB

    precompute_kernel<<<E_, 512, 0, stream>>>(Wd, bd, Wc, bc, Wr, br, emb, Wf, bf,
                                              At, basep);
    main_kernel<<<NBLK, 256, 0, stream>>>(metadata, At, basep, gamma, beta,
                                          (float*)d_out);
}